// Round 3
// baseline (119.892 us; speedup 1.0000x reference)
//
#include <hip/hip_runtime.h>
#include <stdint.h>

// OpenBoundary neighbour list, N=8192, cutoff 0.125, max_neighbours=128.
// R7: 2 dispatches (was 4). No cooperative launch (R6: coop + graph
// capture hangs — barrier object not initialised on replay). Instead a
// hand-rolled grid barrier in OUR workspace, zeroed by the preceding
// memset (stream-ordered):
//   memset : zero cnt[512] + bar (2052 B)
//   fused  : phase B  blocks 0..15 scatter point i ->
//                     cells[cell][atomicAdd(cnt[cell])]; block 0 zeroes
//                     out_max.
//            barrier  all 512 blocks arrive (agent-scope atomic + spin;
//                     co-residency guaranteed: 2 blocks/CU by
//                     __launch_bounds__(512,4) VGPR<=128, LDS 72KB/CU,
//                     16 waves/CU — grid == capacity exactly).
//            phase C  cell-centric neigh (1 block/cell, 8 waves). Stage
//                     27-cell candidate set into LDS once; each wave
//                     tests its rows full-lane. Hits -> per-wave 1KB LDS
//                     bitmap; lane-major enumeration + shfl scan emits
//                     ascending indices (jnp.argwhere order). Row max ->
//                     LDS blkmax -> one agent atomicMax(out_max)/block.

#define CUTOFF2 (0.125f * 0.125f)
constexpr int NCELLS  = 512;   // 8^3
constexpr int CAP     = 64;    // slots/cell; occupancy ~Poisson(16), max~32
constexpr int MAXN    = 128;
constexpr int CANDMAX = 27 * CAP;   // hard bound on staged candidates (27 KB)

__device__ __forceinline__ int ccoord(float v) {
    int c = (int)(v * 8.0f);
    return c > 7 ? 7 : c;
}

__device__ __forceinline__ void grid_barrier(int* bar, int nblocks) {
    __syncthreads();
    if (threadIdx.x == 0) {
        __threadfence();   // release: cells/cnt/out_max visible device-wide
        __hip_atomic_fetch_add(bar, 1, __ATOMIC_ACQ_REL, __HIP_MEMORY_SCOPE_AGENT);
        while (__hip_atomic_load(bar, __ATOMIC_ACQUIRE, __HIP_MEMORY_SCOPE_AGENT)
               < nblocks) {
            __builtin_amdgcn_s_sleep(8);
        }
        __threadfence();   // acquire
    }
    __syncthreads();
}

__global__ __launch_bounds__(512, 4) void fused_kernel(
    const float* __restrict__ pos, int n, int maxn,
    int* __restrict__ to_idx,
    int* __restrict__ cell_out,     // [n, maxn, 3] zeros
    int* __restrict__ out_max,
    int* __restrict__ cnt,          // [512], pre-zeroed
    int* __restrict__ bar,          // [1],  pre-zeroed
    float4* __restrict__ cells)
{
    __shared__ float4   cand[CANDMAX];   // staged stencil candidates
    __shared__ uint32_t bm[8][256];      // per-wave 8192-bit bitmap
    __shared__ int scid[27], scnt[27], soff[28];
    __shared__ int blkmax;

    const int tid  = threadIdx.x;
    const int lane = tid & 63;
    const int wave = tid >> 6;
    const int cell = blockIdx.x;

    // ---- phase B: scatter (blocks 0..15 carry points; rest go to barrier) --
    {
        const int i = cell * 512 + tid;
        if (i < n) {
            float x = pos[i*3], y = pos[i*3+1], z = pos[i*3+2];
            int c = (ccoord(z) * 8 + ccoord(y)) * 8 + ccoord(x);
            int slot = atomicAdd(&cnt[c], 1);
            cells[c * CAP + slot] = make_float4(x, y, z, __int_as_float(i));
        }
        if (cell == 0 && tid == 0) *out_max = 0;
    }

    grid_barrier(bar, NCELLS);

    // ---- phase C: neighbours for cell == blockIdx.x ----
    const int cx = cell & 7, cy = (cell >> 3) & 7, cz = cell >> 6;

    // stencil setup: wave 0, lanes 0..26 load cnts, shfl-scan prefix
    if (tid < 64) {
        int dzz = tid / 9 - 1, dyy = (tid / 3) % 3 - 1, dxx = tid % 3 - 1;
        int xx = cx + dxx, yy = cy + dyy, zz = cz + dzz;
        bool ok = (tid < 27) & ((unsigned)xx <= 7u) &
                  ((unsigned)yy <= 7u) & ((unsigned)zz <= 7u);
        int c = (zz * 8 + yy) * 8 + xx;
        int v = ok ? cnt[c] : 0;
        if (tid < 27) { scid[tid] = ok ? c : -1; scnt[tid] = v; }
        int incl = v;
        #pragma unroll
        for (int d = 1; d < 32; d <<= 1) {
            int o = __shfl_up(incl, d);
            if (lane >= d) incl += o;
        }
        if (tid < 27) soff[tid + 1] = incl;
        if (tid == 0) { soff[0] = 0; blkmax = 0; }
    }
    __syncthreads();

    const int mrows = scnt[13];          // center cell (dz=dy=dx=0) -> idx 13
    const int cbase = soff[13];
    if (mrows == 0) return;              // uniform per block; after barrier

    // stage candidates into LDS: wave j handles stencil cells j, j+8, ...
    for (int j = wave; j < 27; j += 8) {
        int c = scid[j];
        if (c >= 0 && lane < scnt[j])
            cand[soff[j] + lane] = cells[c * CAP + lane];
    }
    __syncthreads();

    const int T = soff[27];
    uint32_t* mybm = bm[wave];

    // row loop: each wave owns rows wave, wave+8, ... of this cell
    for (int r = wave; r < mrows; r += 8) {
        float4 me = cand[cbase + r];          // broadcast read
        const int row = __float_as_int(me.w);

        ((int4*)mybm)[lane] = make_int4(0, 0, 0, 0);   // zero bitmap

        // zero this row's cell_indices slice (96 int4), overlaps with tests
        int4* co = (int4*)(cell_out + (size_t)row * maxn * 3);
        co[lane] = make_int4(0, 0, 0, 0);
        if (lane < 32) co[64 + lane] = make_int4(0, 0, 0, 0);

        // full-lane test loop over LDS candidates, 2x unrolled for ILP
        int s = lane;
        for (; s + 64 < T; s += 128) {
            float4 q0 = cand[s];
            float4 q1 = cand[s + 64];
            float dx0 = q0.x - me.x, dy0 = q0.y - me.y, dz0 = q0.z - me.z;
            float dx1 = q1.x - me.x, dy1 = q1.y - me.y, dz1 = q1.z - me.z;
            float d20 = dx0*dx0 + dy0*dy0 + dz0*dz0;
            float d21 = dx1*dx1 + dy1*dy1 + dz1*dz1;
            int i0 = __float_as_int(q0.w);
            int i1 = __float_as_int(q1.w);
            if (d20 <= CUTOFF2 && i0 != row)
                atomicOr(&mybm[i0 >> 5], 1u << (i0 & 31));
            if (d21 <= CUTOFF2 && i1 != row)
                atomicOr(&mybm[i1 >> 5], 1u << (i1 & 31));
        }
        if (s < T) {
            float4 q = cand[s];
            float ddx = q.x - me.x, ddy = q.y - me.y, ddz = q.z - me.z;
            float d2 = ddx*ddx + ddy*ddy + ddz*ddz;
            int i0 = __float_as_int(q.w);
            if (d2 <= CUTOFF2 && i0 != row)
                atomicOr(&mybm[i0 >> 5], 1u << (i0 & 31));
        }

        // lane-major 128-bit slice -> ascending global index order
        int4 wv = ((int4*)mybm)[lane];
        uint32_t w0 = (uint32_t)wv.x, w1 = (uint32_t)wv.y,
                 w2 = (uint32_t)wv.z, w3 = (uint32_t)wv.w;
        int tc = __popc(w0) + __popc(w1) + __popc(w2) + __popc(w3);

        int inc = tc;
        #pragma unroll
        for (int d = 1; d < 64; d <<= 1) {
            int o = __shfl_up(inc, d);
            if (lane >= d) inc += o;
        }
        const int total = __shfl(inc, 63);   // uncapped neighbour count
        int p = inc - tc;                    // exclusive prefix

        int* out_row = to_idx + (size_t)row * maxn;
        const int bitbase = lane << 7;
        uint32_t wsv[4] = {w0, w1, w2, w3};
        #pragma unroll
        for (int d = 0; d < 4; ++d) {
            uint32_t mm = wsv[d];
            while (mm) {
                int b = __ffs(mm) - 1;
                if (p < MAXN) out_row[p] = bitbase + (d << 5) + b;
                ++p;
                mm &= mm - 1;
            }
        }
        int start = total < MAXN ? total : MAXN;
        for (int q = start + lane; q < MAXN; q += 64) out_row[q] = -1;

        if (lane == 0) atomicMax(&blkmax, total);
    }

    __syncthreads();
    if (tid == 0 && blkmax > 0)
        __hip_atomic_fetch_max(out_max, blkmax, __ATOMIC_RELAXED,
                               __HIP_MEMORY_SCOPE_AGENT);
}

extern "C" void kernel_launch(void* const* d_in, const int* in_sizes, int n_in,
                              void* d_out, int out_size, void* d_ws, size_t ws_size,
                              hipStream_t stream) {
    const float* pos = (const float*)d_in[0];
    int n = in_sizes[0] / 3;                             // 8192
    int maxn = (out_size - 1) / (n * 4);                 // 128

    int* to_idx   = (int*)d_out;
    int* cell_out = to_idx + (size_t)n * maxn;           // [n, maxn, 3]
    int* out_max  = cell_out + (size_t)n * maxn * 3;     // scalar

    // ws: cnt[512] | bar[1] | pad | cells float4[512*64]
    int*    cnt   = (int*)d_ws;
    int*    bar   = cnt + NCELLS;
    float4* cells = (float4*)((char*)d_ws + 4096);

    hipMemsetAsync(d_ws, 0, (NCELLS + 1) * sizeof(int), stream);
    fused_kernel<<<NCELLS, 512, 0, stream>>>(pos, n, maxn, to_idx, cell_out,
                                             out_max, cnt, bar, cells);
}

// Round 4
// 91.981 us; speedup vs baseline: 1.3034x; 1.3034x over previous
//
#include <hip/hip_runtime.h>
#include <stdint.h>

// OpenBoundary neighbour list, N=8192, cutoff 0.125, max_neighbours=128.
// R8: brute-force all-pairs, 2 dispatches (R7's grid-barrier fusion was a
// 62us loss: acquire fence invalidated L2, 2 blocks/CU cap, idle waves).
//   memset : zero out_max (4 B)
//   brute  : 512 blocks x 512 thr; block b owns rows 16b..16b+15, each
//            wave owns 2 rows (2 private 1KB LDS bitmaps). All 8192
//            candidates staged chunk-wise (512 pts = 6KB) into LDS with
//            coalesced loads; inner loop tests 2 rows/candidate
//            (67M pair tests ~ 9 VALU each ~= 12us chip-wide, VALU-bound).
//            Hits -> bitmap atomicOr; lane-major bit enumeration + shfl
//            scan emits ascending indices (jnp.argwhere order). Row's
//            cell_indices[128][3] slice zeroed in-kernel (overlaps with
//            compute). Per-block max -> one device atomicMax(out_max).
// No cells/cnt arrays, no scatter, no barrier, ws unused.

#define CUTOFF2 (0.125f * 0.125f)
constexpr int MAXN   = 128;
constexpr int CHUNK  = 512;               // candidates staged per chunk
constexpr int WAVES  = 8;
constexpr int ROWS_PER_BLOCK = WAVES * 2; // 16

__global__ __launch_bounds__(512) void brute_kernel(
    const float* __restrict__ pos, int n, int maxn,
    int* __restrict__ to_idx,
    int* __restrict__ cell_out,     // [n, maxn, 3] zeros
    int* __restrict__ out_max)
{
    __shared__ float    sh[CHUNK * 3];        // 6 KB staged coords
    __shared__ uint32_t bm[WAVES][2][256];    // 16 KB: 2 bitmaps / wave
    __shared__ int blkmax;

    const int tid  = threadIdx.x;
    const int lane = tid & 63;
    const int wave = tid >> 6;

    const int rowA = blockIdx.x * ROWS_PER_BLOCK + wave * 2;
    const int rowB = rowA + 1;

    // zero this wave's two bitmaps (1 int4 per lane per bitmap)
    ((int4*)&bm[wave][0][0])[lane] = make_int4(0, 0, 0, 0);
    ((int4*)&bm[wave][1][0])[lane] = make_int4(0, 0, 0, 0);
    if (tid == 0) blkmax = 0;

    const float ax = pos[rowA*3], ay = pos[rowA*3+1], az = pos[rowA*3+2];
    const float bx = pos[rowB*3], by = pos[rowB*3+1], bz = pos[rowB*3+2];

    // zero both rows' cell_indices slices (96 int4 each); fire-and-forget,
    // overlaps with the candidate loop below
    {
        int4* coA = (int4*)(cell_out + (size_t)rowA * maxn * 3);
        int4* coB = (int4*)(cell_out + (size_t)rowB * maxn * 3);
        coA[lane] = make_int4(0, 0, 0, 0);
        coB[lane] = make_int4(0, 0, 0, 0);
        if (lane < 32) {
            coA[64 + lane] = make_int4(0, 0, 0, 0);
            coB[64 + lane] = make_int4(0, 0, 0, 0);
        }
    }

    // ---- candidate loop: all n points, staged in CHUNK-sized LDS tiles ----
    const int nchunk = n / CHUNK;     // 16
    for (int c = 0; c < nchunk; ++c) {
        __syncthreads();
        const float* src = pos + (size_t)c * (CHUNK * 3);
        sh[tid]        = src[tid];
        sh[tid +  512] = src[tid +  512];
        sh[tid + 1024] = src[tid + 1024];
        __syncthreads();

        const int gbase = c * CHUNK;
        #pragma unroll
        for (int it = 0; it < CHUNK / 64; ++it) {   // 8 iterations
            const int j = it * 64 + lane;
            const float x = sh[j*3], y = sh[j*3+1], z = sh[j*3+2];
            const int g = gbase + j;
            const float dxa = x - ax, dya = y - ay, dza = z - az;
            const float dxb = x - bx, dyb = y - by, dzb = z - bz;
            const float d2a = dxa*dxa + dya*dya + dza*dza;
            const float d2b = dxb*dxb + dyb*dyb + dzb*dzb;
            if (d2a <= CUTOFF2 && g != rowA)
                atomicOr(&bm[wave][0][g >> 5], 1u << (g & 31));
            if (d2b <= CUTOFF2 && g != rowB)
                atomicOr(&bm[wave][1][g >> 5], 1u << (g & 31));
        }
    }
    // no barrier needed: each wave reads only its own bitmaps, and a wave's
    // LDS ops complete in issue order (same pattern as R4/R5, verified).

    // ---- epilogue: per owned row, bitmap -> ascending index list ----
    #pragma unroll
    for (int s = 0; s < 2; ++s) {
        const int row = rowA + s;

        int4 wv = ((int4*)&bm[wave][s][0])[lane];
        uint32_t w0 = (uint32_t)wv.x, w1 = (uint32_t)wv.y,
                 w2 = (uint32_t)wv.z, w3 = (uint32_t)wv.w;
        int tc = __popc(w0) + __popc(w1) + __popc(w2) + __popc(w3);

        int inc = tc;
        #pragma unroll
        for (int d = 1; d < 64; d <<= 1) {
            int o = __shfl_up(inc, d);
            if (lane >= d) inc += o;
        }
        const int total = __shfl(inc, 63);   // uncapped neighbour count
        int p = inc - tc;                    // exclusive prefix

        int* out_row = to_idx + (size_t)row * maxn;
        const int bitbase = lane << 7;
        uint32_t wsv[4] = {w0, w1, w2, w3};
        #pragma unroll
        for (int d = 0; d < 4; ++d) {
            uint32_t mm = wsv[d];
            while (mm) {
                int b = __ffs(mm) - 1;
                if (p < MAXN) out_row[p] = bitbase + (d << 5) + b;
                ++p;
                mm &= mm - 1;
            }
        }
        int start = total < MAXN ? total : MAXN;
        for (int q = start + lane; q < MAXN; q += 64) out_row[q] = -1;

        if (lane == 0) atomicMax(&blkmax, total);
    }

    __syncthreads();
    if (tid == 0) atomicMax(out_max, blkmax);
}

extern "C" void kernel_launch(void* const* d_in, const int* in_sizes, int n_in,
                              void* d_out, int out_size, void* d_ws, size_t ws_size,
                              hipStream_t stream) {
    const float* pos = (const float*)d_in[0];
    int n = in_sizes[0] / 3;                             // 8192
    int maxn = (out_size - 1) / (n * 4);                 // 128

    int* to_idx   = (int*)d_out;
    int* cell_out = to_idx + (size_t)n * maxn;           // [n, maxn, 3]
    int* out_max  = cell_out + (size_t)n * maxn * 3;     // scalar

    hipMemsetAsync(out_max, 0, sizeof(int), stream);
    brute_kernel<<<n / ROWS_PER_BLOCK, 512, 0, stream>>>(
        pos, n, maxn, to_idx, cell_out, out_max);
}

// Round 5
// 79.235 us; speedup vs baseline: 1.5131x; 1.1609x over previous
//
#include <hip/hip_runtime.h>
#include <stdint.h>

// OpenBoundary neighbour list, N=8192, cutoff 0.125, max_neighbours=128.
// R9: scatter-free cell-centric kernel, 2 dispatches:
//   memset : zero out_max (4 B)
//   cell   : 1 block (512 thr, 8 waves) per cell (8^3 grid, cell=cutoff).
//     phase 1: scan all 8192 points (96 KB, L2-resident; 49 MB aggregate
//              ~= 1.5 us chip-wide). Wave-compact stencil-AABB hits
//              (~432) into cand[] and own-cell rows (~16) into ownp[]
//              via ballot+popc, one LDS atomicAdd per wave per chunk.
//              Replaces R5's memset+scatter dispatches and cells[] ws.
//     phase 2: R5's proven row loop — each wave owns rows wave, wave+8,..;
//              full-lane test loop over cand[] (~7 iters), hits -> per-wave
//              1KB LDS bitmap (atomicOr); lane-major bit enumeration +
//              shfl scan emits ascending indices (jnp.argwhere order);
//              zeroes the row's cell_indices[128][3] slice (overlaps).
//     epilogue: block max -> one device atomicMax(out_max) (replaces
//              partial[]+maxred).
// ws unused.

#define CUTOFF2 (0.125f * 0.125f)
constexpr int MAXN    = 128;
constexpr int CANDMAX = 27 * 64;   // stencil hits hard bound (27 KB LDS)
constexpr int OWNCAP  = 64;        // own-cell rows bound (input max ~32)

__device__ __forceinline__ int ccoord(float v) {
    int c = (int)(v * 8.0f);
    return c > 7 ? 7 : c;
}

__global__ __launch_bounds__(512) void cell_kernel(
    const float* __restrict__ pos, int n, int maxn,
    int* __restrict__ to_idx,
    int* __restrict__ cell_out,     // [n, maxn, 3] zeros
    int* __restrict__ out_max)
{
    __shared__ float4   cand[CANDMAX];   // staged stencil candidates
    __shared__ float4   ownp[OWNCAP];    // this cell's rows
    __shared__ uint32_t bm[8][256];      // per-wave 8192-bit bitmap
    __shared__ int nc, nown, blkmax;

    const int tid  = threadIdx.x;
    const int lane = tid & 63;
    const int wave = tid >> 6;
    const int cell = blockIdx.x;
    const int cx = cell & 7, cy = (cell >> 3) & 7, cz = cell >> 6;

    if (tid == 0) { nc = 0; nown = 0; blkmax = 0; }
    __syncthreads();

    // ---- phase 1: scan + wave-compact (16 chunks of 512 points) ----
    for (int base = 0; base < n; base += 512) {
        const int i = base + tid;
        const float x = pos[i*3], y = pos[i*3+1], z = pos[i*3+2];
        const int ccx = ccoord(x), ccy = ccoord(y), ccz = ccoord(z);
        const bool inb = ((unsigned)(ccx - cx + 1) <= 2u) &
                         ((unsigned)(ccy - cy + 1) <= 2u) &
                         ((unsigned)(ccz - cz + 1) <= 2u);
        const bool own = (ccx == cx) & (ccy == cy) & (ccz == cz);

        uint64_t m = __ballot(inb);
        if (m) {
            const int leader = __ffsll((unsigned long long)m) - 1;
            int b0;
            if (lane == leader) b0 = atomicAdd(&nc, __popcll(m));
            b0 = __shfl(b0, leader);
            if (inb) {
                int off = b0 + __popcll(m & ((1ULL << lane) - 1));
                cand[off] = make_float4(x, y, z, __int_as_float(i));
            }
        }
        uint64_t mo = __ballot(own);
        if (mo) {
            const int leader = __ffsll((unsigned long long)mo) - 1;
            int b0;
            if (lane == leader) b0 = atomicAdd(&nown, __popcll(mo));
            b0 = __shfl(b0, leader);
            if (own) {
                int off = b0 + __popcll(mo & ((1ULL << lane) - 1));
                ownp[off] = make_float4(x, y, z, __int_as_float(i));
            }
        }
    }
    __syncthreads();

    const int T     = nc;
    const int mrows = nown;
    uint32_t* mybm  = bm[wave];

    // ---- phase 2: row loop — each wave owns rows wave, wave+8, ... ----
    for (int r = wave; r < mrows; r += 8) {
        const float4 me = ownp[r];            // broadcast read
        const int row = __float_as_int(me.w);

        ((int4*)mybm)[lane] = make_int4(0, 0, 0, 0);   // zero bitmap

        // zero this row's cell_indices slice (96 int4), overlaps with tests
        int4* co = (int4*)(cell_out + (size_t)row * maxn * 3);
        co[lane] = make_int4(0, 0, 0, 0);
        if (lane < 32) co[64 + lane] = make_int4(0, 0, 0, 0);

        // full-lane test loop over LDS candidates, 2x unrolled for ILP
        int s = lane;
        for (; s + 64 < T; s += 128) {
            float4 q0 = cand[s];
            float4 q1 = cand[s + 64];
            float dx0 = q0.x - me.x, dy0 = q0.y - me.y, dz0 = q0.z - me.z;
            float dx1 = q1.x - me.x, dy1 = q1.y - me.y, dz1 = q1.z - me.z;
            float d20 = dx0*dx0 + dy0*dy0 + dz0*dz0;
            float d21 = dx1*dx1 + dy1*dy1 + dz1*dz1;
            int i0 = __float_as_int(q0.w);
            int i1 = __float_as_int(q1.w);
            if (d20 <= CUTOFF2 && i0 != row)
                atomicOr(&mybm[i0 >> 5], 1u << (i0 & 31));
            if (d21 <= CUTOFF2 && i1 != row)
                atomicOr(&mybm[i1 >> 5], 1u << (i1 & 31));
        }
        if (s < T) {
            float4 q = cand[s];
            float ddx = q.x - me.x, ddy = q.y - me.y, ddz = q.z - me.z;
            float d2 = ddx*ddx + ddy*ddy + ddz*ddz;
            int i0 = __float_as_int(q.w);
            if (d2 <= CUTOFF2 && i0 != row)
                atomicOr(&mybm[i0 >> 5], 1u << (i0 & 31));
        }

        // lane-major 128-bit slice -> ascending global index order
        int4 wv = ((int4*)mybm)[lane];
        uint32_t w0 = (uint32_t)wv.x, w1 = (uint32_t)wv.y,
                 w2 = (uint32_t)wv.z, w3 = (uint32_t)wv.w;
        int tc = __popc(w0) + __popc(w1) + __popc(w2) + __popc(w3);

        int inc = tc;
        #pragma unroll
        for (int d = 1; d < 64; d <<= 1) {
            int o = __shfl_up(inc, d);
            if (lane >= d) inc += o;
        }
        const int total = __shfl(inc, 63);   // uncapped neighbour count
        int p = inc - tc;                    // exclusive prefix

        int* out_row = to_idx + (size_t)row * maxn;
        const int bitbase = lane << 7;
        uint32_t wsv[4] = {w0, w1, w2, w3};
        #pragma unroll
        for (int d = 0; d < 4; ++d) {
            uint32_t mm = wsv[d];
            while (mm) {
                int b = __ffs(mm) - 1;
                if (p < MAXN) out_row[p] = bitbase + (d << 5) + b;
                ++p;
                mm &= mm - 1;
            }
        }
        int start = total < MAXN ? total : MAXN;
        for (int q = start + lane; q < MAXN; q += 64) out_row[q] = -1;

        if (lane == 0) atomicMax(&blkmax, total);
    }

    __syncthreads();
    if (tid == 0) atomicMax(out_max, blkmax);
}

extern "C" void kernel_launch(void* const* d_in, const int* in_sizes, int n_in,
                              void* d_out, int out_size, void* d_ws, size_t ws_size,
                              hipStream_t stream) {
    const float* pos = (const float*)d_in[0];
    int n = in_sizes[0] / 3;                             // 8192
    int maxn = (out_size - 1) / (n * 4);                 // 128

    int* to_idx   = (int*)d_out;
    int* cell_out = to_idx + (size_t)n * maxn;           // [n, maxn, 3]
    int* out_max  = cell_out + (size_t)n * maxn * 3;     // scalar

    hipMemsetAsync(out_max, 0, sizeof(int), stream);
    cell_kernel<<<512, 512, 0, stream>>>(pos, n, maxn,
                                         to_idx, cell_out, out_max);
}

// Round 6
// 76.028 us; speedup vs baseline: 1.5769x; 1.0422x over previous
//
#include <hip/hip_runtime.h>
#include <stdint.h>

// OpenBoundary neighbour list, N=8192, cutoff 0.125, max_neighbours=128.
// R10: R9 + vectorized phase 1. 2 dispatches:
//   memset : zero out_max (4 B)
//   cell   : 1 block (512 thr, 8 waves) per cell (8^3 grid, cell=cutoff).
//     phase 1: scan all 8192 points in 4 chunks of 2048; thread t reads
//              3 coalesced float4 = 4 points, classifies them against the
//              3x3x3 stencil AABB, and the wave compacts hits into cand[]
//              with ONE shfl prefix-scan + ONE leader LDS-atomic per
//              chunk (R9 did 16 chunks x 2 ballot-compact rounds).
//              Per-wave candidate runs stay lane-major ascending; the
//              bitmap epilogue absorbs cross-wave disorder.
//     own-rows: derived from cand[] in one short post-pass (order of
//              rows is irrelevant — each row writes a disjoint slice).
//     phase 2: proven row loop — each wave owns rows wave, wave+8, ..;
//              full-lane test loop over cand[] (~7 iters), hits -> per-
//              wave 1KB LDS bitmap (atomicOr); lane-major bit enumeration
//              + shfl scan emits ascending indices (jnp.argwhere order);
//              zeroes the row's cell_indices[128][3] slice (overlaps).
//     epilogue: block max -> one device atomicMax(out_max).
// ws unused.

#define CUTOFF2 (0.125f * 0.125f)
constexpr int MAXN    = 128;
constexpr int CANDMAX = 27 * 64;   // stencil hits hard bound (27 KB LDS)
constexpr int OWNCAP  = 64;        // own-cell rows bound (input max ~32)

__device__ __forceinline__ int ccoord(float v) {
    int c = (int)(v * 8.0f);
    return c > 7 ? 7 : c;
}

__global__ __launch_bounds__(512) void cell_kernel(
    const float* __restrict__ pos, int n, int maxn,
    int* __restrict__ to_idx,
    int* __restrict__ cell_out,     // [n, maxn, 3] zeros
    int* __restrict__ out_max)
{
    __shared__ float4   cand[CANDMAX];   // staged stencil candidates
    __shared__ float4   ownp[OWNCAP];    // this cell's rows
    __shared__ uint32_t bm[8][256];      // per-wave 8192-bit bitmap
    __shared__ int nc, nown, blkmax;

    const int tid  = threadIdx.x;
    const int lane = tid & 63;
    const int wave = tid >> 6;
    const int cell = blockIdx.x;
    const int cx = cell & 7, cy = (cell >> 3) & 7, cz = cell >> 6;

    if (tid == 0) { nc = 0; nown = 0; blkmax = 0; }
    __syncthreads();

    // ---- phase 1: 4 chunks of 2048 points; 4 points per thread/chunk ----
    const float4* p4 = (const float4*)pos;
    const int nchunk = n >> 11;                   // n / 2048
    for (int k = 0; k < nchunk; ++k) {
        const int slot = k * 512 + tid;           // 4-point group index
        const int m0 = slot * 3;
        const float4 a = p4[m0], b = p4[m0 + 1], c = p4[m0 + 2];
        const float X[4] = {a.x, a.w, b.z, c.y};
        const float Y[4] = {a.y, b.x, b.w, c.z};
        const float Z[4] = {a.z, b.y, c.x, c.w};
        const int gbase = slot * 4;

        bool hit[4];
        int h = 0;
        #pragma unroll
        for (int j = 0; j < 4; ++j) {
            const int ccx = ccoord(X[j]), ccy = ccoord(Y[j]), ccz = ccoord(Z[j]);
            hit[j] = ((unsigned)(ccx - cx + 1) <= 2u) &
                     ((unsigned)(ccy - cy + 1) <= 2u) &
                     ((unsigned)(ccz - cz + 1) <= 2u);
            h += hit[j];
        }

        // wave-wide exclusive offsets via inclusive shfl scan
        int incl = h;
        #pragma unroll
        for (int d = 1; d < 64; d <<= 1) {
            int o = __shfl_up(incl, d);
            if (lane >= d) incl += o;
        }
        const int wtot = __shfl(incl, 63);
        int b0 = 0;
        if (lane == 63 && wtot) b0 = atomicAdd(&nc, wtot);
        b0 = __shfl(b0, 63);

        int off = b0 + incl - h;
        #pragma unroll
        for (int j = 0; j < 4; ++j) {
            if (hit[j]) {
                cand[off] = make_float4(X[j], Y[j], Z[j],
                                        __int_as_float(gbase + j));
                ++off;
            }
        }
    }
    __syncthreads();

    const int T = nc;

    // ---- own-rows: one short pass over cand[] (row order irrelevant) ----
    for (int t = tid; t < T; t += 512) {
        const float4 q = cand[t];
        if (ccoord(q.x) == cx && ccoord(q.y) == cy && ccoord(q.z) == cz) {
            const int s = atomicAdd(&nown, 1);
            ownp[s] = q;
        }
    }
    __syncthreads();

    const int mrows = nown;
    uint32_t* mybm  = bm[wave];

    // ---- phase 2: row loop — each wave owns rows wave, wave+8, ... ----
    for (int r = wave; r < mrows; r += 8) {
        const float4 me = ownp[r];            // broadcast read
        const int row = __float_as_int(me.w);

        ((int4*)mybm)[lane] = make_int4(0, 0, 0, 0);   // zero bitmap

        // zero this row's cell_indices slice (96 int4), overlaps with tests
        int4* co = (int4*)(cell_out + (size_t)row * maxn * 3);
        co[lane] = make_int4(0, 0, 0, 0);
        if (lane < 32) co[64 + lane] = make_int4(0, 0, 0, 0);

        // full-lane test loop over LDS candidates, 2x unrolled for ILP
        int s = lane;
        for (; s + 64 < T; s += 128) {
            float4 q0 = cand[s];
            float4 q1 = cand[s + 64];
            float dx0 = q0.x - me.x, dy0 = q0.y - me.y, dz0 = q0.z - me.z;
            float dx1 = q1.x - me.x, dy1 = q1.y - me.y, dz1 = q1.z - me.z;
            float d20 = dx0*dx0 + dy0*dy0 + dz0*dz0;
            float d21 = dx1*dx1 + dy1*dy1 + dz1*dz1;
            int i0 = __float_as_int(q0.w);
            int i1 = __float_as_int(q1.w);
            if (d20 <= CUTOFF2 && i0 != row)
                atomicOr(&mybm[i0 >> 5], 1u << (i0 & 31));
            if (d21 <= CUTOFF2 && i1 != row)
                atomicOr(&mybm[i1 >> 5], 1u << (i1 & 31));
        }
        if (s < T) {
            float4 q = cand[s];
            float ddx = q.x - me.x, ddy = q.y - me.y, ddz = q.z - me.z;
            float d2 = ddx*ddx + ddy*ddy + ddz*ddz;
            int i0 = __float_as_int(q.w);
            if (d2 <= CUTOFF2 && i0 != row)
                atomicOr(&mybm[i0 >> 5], 1u << (i0 & 31));
        }

        // lane-major 128-bit slice -> ascending global index order
        int4 wv = ((int4*)mybm)[lane];
        uint32_t w0 = (uint32_t)wv.x, w1 = (uint32_t)wv.y,
                 w2 = (uint32_t)wv.z, w3 = (uint32_t)wv.w;
        int tc = __popc(w0) + __popc(w1) + __popc(w2) + __popc(w3);

        int inc = tc;
        #pragma unroll
        for (int d = 1; d < 64; d <<= 1) {
            int o = __shfl_up(inc, d);
            if (lane >= d) inc += o;
        }
        const int total = __shfl(inc, 63);   // uncapped neighbour count
        int p = inc - tc;                    // exclusive prefix

        int* out_row = to_idx + (size_t)row * maxn;
        const int bitbase = lane << 7;
        uint32_t wsv[4] = {w0, w1, w2, w3};
        #pragma unroll
        for (int d = 0; d < 4; ++d) {
            uint32_t mm = wsv[d];
            while (mm) {
                int b = __ffs(mm) - 1;
                if (p < MAXN) out_row[p] = bitbase + (d << 5) + b;
                ++p;
                mm &= mm - 1;
            }
        }
        int start = total < MAXN ? total : MAXN;
        for (int q = start + lane; q < MAXN; q += 64) out_row[q] = -1;

        if (lane == 0) atomicMax(&blkmax, total);
    }

    __syncthreads();
    if (tid == 0) atomicMax(out_max, blkmax);
}

extern "C" void kernel_launch(void* const* d_in, const int* in_sizes, int n_in,
                              void* d_out, int out_size, void* d_ws, size_t ws_size,
                              hipStream_t stream) {
    const float* pos = (const float*)d_in[0];
    int n = in_sizes[0] / 3;                             // 8192
    int maxn = (out_size - 1) / (n * 4);                 // 128

    int* to_idx   = (int*)d_out;
    int* cell_out = to_idx + (size_t)n * maxn;           // [n, maxn, 3]
    int* out_max  = cell_out + (size_t)n * maxn * 3;     // scalar

    hipMemsetAsync(out_max, 0, sizeof(int), stream);
    cell_kernel<<<512, 512, 0, stream>>>(pos, n, maxn,
                                         to_idx, cell_out, out_max);
}